// Round 5
// baseline (144.915 us; speedup 1.0000x reference)
//
#include <hip/hip_runtime.h>
#include <hip/hip_bf16.h>
#include <math.h>

#define NROWS 8192
#define DIM   768
#define NKS   (DIM / 32)         // 24 k-slices of 32
#define NRG   (NROWS / 16)       // 512 row-groups of 16
// pack: frag(rg, ks) at ((rg*NKS)+ks)*1024 + lane*16 ; lane l holds
// rows r = l&15, k = ks*32 + (l>>4)*8 .. +8  (bf16x8) — the exact MFMA
// A/B fragment for mfma_f32_16x16x32_bf16 (operands symmetric for X·X^T).
#define NP    (NROWS / 128)      // 64 i-panels (128 rows)
#define NTILE 4160               // sum_{p<64} (128 - 2p) wave-tiles (q >= 2p)
#define NBLK  (NTILE / 4)        // 1040 blocks of 4 independent waves
#define PACKB ((size_t)NRG * NKS * 1024)   // 12.58 MB

typedef __attribute__((ext_vector_type(4))) float  f32x4;
typedef __attribute__((ext_vector_type(8))) __bf16 bf16x8;
typedef __attribute__((ext_vector_type(4))) __bf16 bf16x4;

// ---------------------------------------------------------------------------
// Kernel A: pack + prep. Block per 16-row group; wave w handles 6 k-slices.
// Lane l: reads rows rg*16+(l&15), 8 consecutive f32 at k = ks*32+(l>>4)*8
// (lanes {r,r+16,r+32,r+48} cover one 128B row segment), converts to bf16x8,
// stores at frag base + l*16 (1KB contiguous per wave -> perfect coalescing).
// Also accumulates exact f32 sq-norms and inits minbits.
// ---------------------------------------------------------------------------
__global__ __launch_bounds__(256) void koleo_pack(const float* __restrict__ X,
                                                  float* __restrict__ sq,
                                                  unsigned int* __restrict__ minbits,
                                                  char* __restrict__ xbf) {
  __shared__ float part[4][16];
  const int rg   = blockIdx.x;             // 0..511
  const int lane = threadIdx.x & 63;
  const int w    = threadIdx.x >> 6;       // 0..3
  const int r    = lane & 15;
  const int qq   = lane >> 4;              // k-quarter
  const float* xrow = X + (size_t)(rg * 16 + r) * DIM;
  char* fb = xbf + (size_t)rg * NKS * 1024 + lane * 16;
  float s = 0.f;
#pragma unroll
  for (int i = 0; i < 6; ++i) {
    const int ks = w * 6 + i;
    const float* src = xrow + ks * 32 + qq * 8;
    f32x4 v0 = *(const f32x4*)(src);
    f32x4 v1 = *(const f32x4*)(src + 4);
    s += v0.x * v0.x + v0.y * v0.y + v0.z * v0.z + v0.w * v0.w;
    s += v1.x * v1.x + v1.y * v1.y + v1.z * v1.z + v1.w * v1.w;
    bf16x8 h;
    h[0] = (__bf16)v0.x; h[1] = (__bf16)v0.y; h[2] = (__bf16)v0.z; h[3] = (__bf16)v0.w;
    h[4] = (__bf16)v1.x; h[5] = (__bf16)v1.y; h[6] = (__bf16)v1.z; h[7] = (__bf16)v1.w;
    *(bf16x8*)(fb + ks * 1024) = h;
  }
  // reduce the 4 k-quarters of each row within the wave
  s += __shfl_xor(s, 16, 64);
  s += __shfl_xor(s, 32, 64);
  if (lane < 16) part[w][r] = s;
  __syncthreads();
  if (threadIdx.x < 16) {
    const float t = part[0][threadIdx.x] + part[1][threadIdx.x] +
                    part[2][threadIdx.x] + part[3][threadIdx.x];
    sq[rg * 16 + threadIdx.x]      = t;
    minbits[rg * 16 + threadIdx.x] = 0x7F800000u;    // +inf
  }
}

// ---------------------------------------------------------------------------
// Kernel B: per-WAVE 128x64 Gram tiles straight from the packed buffer.
// No LDS, no barriers: each wave register-double-buffers 12 fragments
// (8 A + 4 B) and runs 32 MFMA per k-slice. Tiles (p,q) with q >= 2p;
// min is idempotent so symmetric double-count inside diagonal-overlap
// tiles is harmless; gi==gj masked. Row-min AND col-min via atomicMin.
// ---------------------------------------------------------------------------
#define MFMA_SET(A, B)                                                        \
  _Pragma("unroll") for (int m = 0; m < 8; ++m)                               \
  _Pragma("unroll") for (int n = 0; n < 4; ++n)                               \
    acc[m][n] = __builtin_amdgcn_mfma_f32_16x16x32_bf16(A[m], B[n], acc[m][n], 0, 0, 0);

#define LOAD_SET(A, B, ks)                                                    \
  _Pragma("unroll") for (int m = 0; m < 8; ++m)                               \
    A[m] = *(const bf16x8*)(bA + (size_t)(m * NKS + (ks)) * 1024);            \
  _Pragma("unroll") for (int n = 0; n < 4; ++n)                               \
    B[n] = *(const bf16x8*)(bB + (size_t)(n * NKS + (ks)) * 1024);

__global__ __launch_bounds__(256, 2) void koleo_frag(const char* __restrict__ xbf,
                                                     const float* __restrict__ sq,
                                                     unsigned int* __restrict__ minbits) {
  // bijective XCD swizzle: 1040 = 8 * 130
  const int raw  = blockIdx.x;
  const int b    = (raw & 7) * (NBLK / 8) + (raw >> 3);
  const int lane = threadIdx.x & 63;
  const int w    = threadIdx.x >> 6;

  // wave-tile index -> (p, q): p-major rows of length 128-2p
  int rem = b * 4 + w, p = 0, rowlen = 128;
  while (rem >= rowlen) { rem -= rowlen; ++p; rowlen -= 2; }
  const int q = 2 * p + rem;

  const char* bA = xbf + (size_t)(p * 8) * NKS * 1024 + lane * 16;
  const char* bB = xbf + (size_t)(q * 4) * NKS * 1024 + lane * 16;

  f32x4 acc[8][4] = {};
  bf16x8 a0[8], b0[4], a1[8], b1[4];

  LOAD_SET(a0, b0, 0);
  for (int t = 0; t < 12; ++t) {           // 2 k-slices per iteration
    LOAD_SET(a1, b1, 2 * t + 1);
    MFMA_SET(a0, b0);
    if (t < 11) { LOAD_SET(a0, b0, 2 * t + 2); }
    MFMA_SET(a1, b1);
  }

  // ---- epilogue: d2, diagonal mask, row-min + col-min, atomicMin ----------
  // C/D layout (m89): col = lane&15, row = (lane>>4)*4 + reg
  const int cg = lane >> 4;
  const int cl = lane & 15;
  const int i0 = p * 128, j0 = q * 64;
  float sqj[4], colmin[4];
#pragma unroll
  for (int n = 0; n < 4; ++n) {
    sqj[n]    = sq[j0 + n * 16 + cl];
    colmin[n] = INFINITY;
  }
#pragma unroll
  for (int m = 0; m < 8; ++m) {
#pragma unroll
    for (int r = 0; r < 4; ++r) {
      const int gi = i0 + m * 16 + cg * 4 + r;
      const float si = sq[gi];
      float rowmin = INFINITY;
#pragma unroll
      for (int n = 0; n < 4; ++n) {
        const int gj = j0 + n * 16 + cl;
        float d2 = si + sqj[n] - 2.0f * acc[m][n][r];
        d2 = fmaxf(d2, 0.0f);
        if (gi == gj) d2 = INFINITY;
        rowmin    = fminf(rowmin, d2);
        colmin[n] = fminf(colmin[n], d2);
      }
      rowmin = fminf(rowmin, __shfl_xor(rowmin, 1, 64));
      rowmin = fminf(rowmin, __shfl_xor(rowmin, 2, 64));
      rowmin = fminf(rowmin, __shfl_xor(rowmin, 4, 64));
      rowmin = fminf(rowmin, __shfl_xor(rowmin, 8, 64));
      if (cl == 0)
        atomicMin(minbits + gi, __float_as_uint(rowmin));
    }
  }
#pragma unroll
  for (int n = 0; n < 4; ++n) {
    float cm = colmin[n];
    cm = fminf(cm, __shfl_xor(cm, 16, 64));
    cm = fminf(cm, __shfl_xor(cm, 32, 64));
    if (cg == 0)
      atomicMin(minbits + j0 + n * 16 + cl, __float_as_uint(cm));
  }
}

// ---------------------------------------------------------------------------
// Fallback (ws too small): f32 load + in-loop cvt staging, 128^2 tiles.
// ---------------------------------------------------------------------------
#define NT128 (NROWS / 128)
__global__ __launch_bounds__(256) void koleo_prep_fb(const float* __restrict__ X,
                                                     float* __restrict__ sq,
                                                     unsigned int* __restrict__ minbits) {
  const int row  = blockIdx.x * 4 + (threadIdx.x >> 6);
  const int lane = threadIdx.x & 63;
  const float* xr = X + (size_t)row * DIM;
  float s = 0.f;
#pragma unroll
  for (int i = 0; i < 3; ++i) {
    f32x4 v = *(const f32x4*)(xr + lane * 4 + i * 256);
    s += v.x * v.x + v.y * v.y + v.z * v.z + v.w * v.w;
  }
#pragma unroll
  for (int m = 32; m >= 1; m >>= 1) s += __shfl_xor(s, m, 64);
  if (lane == 0) { sq[row] = s; minbits[row] = 0x7F800000u; }
}

__global__ __launch_bounds__(256) void koleo_tile_fb(const float* __restrict__ X,
                                                     const float* __restrict__ sq,
                                                     unsigned int* __restrict__ minbits) {
  __shared__ __align__(16) char sA[16384];
  __shared__ __align__(16) char sB[16384];
  int rem = blockIdx.x, ti = 0, rowlen = NT128;
  while (rem >= rowlen) { rem -= rowlen; ++ti; --rowlen; }
  const int tj = ti + rem;
  const int i0 = ti * 128, j0 = tj * 128;
  const int tid = threadIdx.x, lane = tid & 63, wave = tid >> 6;
  const int wr = wave >> 1, wc = wave & 1;
  f32x4 acc[4][4] = {};
  for (int k0 = 0; k0 < DIM; k0 += 64) {
    __syncthreads();
#pragma unroll
    for (int it = 0; it < 8; ++it) {
      const int idx = tid + it * 256;
      const int r = idx >> 4, c4 = idx & 15;
      f32x4 va = *(const f32x4*)(X + (size_t)(i0 + r) * DIM + k0 + c4 * 4);
      f32x4 vb = *(const f32x4*)(X + (size_t)(j0 + r) * DIM + k0 + c4 * 4);
      bf16x4 ha, hb;
      ha[0] = (__bf16)va.x; ha[1] = (__bf16)va.y; ha[2] = (__bf16)va.z; ha[3] = (__bf16)va.w;
      hb[0] = (__bf16)vb.x; hb[1] = (__bf16)vb.y; hb[2] = (__bf16)vb.z; hb[3] = (__bf16)vb.w;
      int off = (r * 128 + c4 * 8) ^ ((r & 7) << 4);
      *(bf16x4*)(sA + off) = ha;
      *(bf16x4*)(sB + off) = hb;
    }
    __syncthreads();
#pragma unroll
    for (int ks = 0; ks < 2; ++ks) {
      bf16x8 af[4], bfr[4];
#pragma unroll
      for (int m = 0; m < 4; ++m) {
        const int ra = wr * 64 + m * 16 + (lane & 15);
        af[m]  = *(const bf16x8*)(sA + ((ra * 128 + ks * 64 + (lane >> 4) * 16) ^ ((ra & 7) << 4)));
        const int rb2 = wc * 64 + m * 16 + (lane & 15);
        bfr[m] = *(const bf16x8*)(sB + ((rb2 * 128 + ks * 64 + (lane >> 4) * 16) ^ ((rb2 & 7) << 4)));
      }
#pragma unroll
      for (int m = 0; m < 4; ++m)
#pragma unroll
        for (int n = 0; n < 4; ++n)
          acc[m][n] = __builtin_amdgcn_mfma_f32_16x16x32_bf16(af[m], bfr[n], acc[m][n], 0, 0, 0);
    }
  }
  const int cg = lane >> 4, cl = lane & 15;
  float sqj[4], colmin[4];
#pragma unroll
  for (int n = 0; n < 4; ++n) { sqj[n] = sq[j0 + wc * 64 + n * 16 + cl]; colmin[n] = INFINITY; }
#pragma unroll
  for (int m = 0; m < 4; ++m) {
#pragma unroll
    for (int r = 0; r < 4; ++r) {
      const int gi = i0 + wr * 64 + m * 16 + cg * 4 + r;
      const float si = sq[gi];
      float rowmin = INFINITY;
#pragma unroll
      for (int n = 0; n < 4; ++n) {
        const int gj = j0 + wc * 64 + n * 16 + cl;
        float d2 = si + sqj[n] - 2.0f * acc[m][n][r];
        d2 = fmaxf(d2, 0.0f);
        if (gi == gj) d2 = INFINITY;
        rowmin = fminf(rowmin, d2);
        colmin[n] = fminf(colmin[n], d2);
      }
      rowmin = fminf(rowmin, __shfl_xor(rowmin, 1, 64));
      rowmin = fminf(rowmin, __shfl_xor(rowmin, 2, 64));
      rowmin = fminf(rowmin, __shfl_xor(rowmin, 4, 64));
      rowmin = fminf(rowmin, __shfl_xor(rowmin, 8, 64));
      if (cl == 0) atomicMin(minbits + gi, __float_as_uint(rowmin));
    }
  }
  if (ti != tj) {
#pragma unroll
    for (int n = 0; n < 4; ++n) {
      float cm = colmin[n];
      cm = fminf(cm, __shfl_xor(cm, 16, 64));
      cm = fminf(cm, __shfl_xor(cm, 32, 64));
      if (cg == 0) atomicMin(minbits + j0 + wc * 64 + n * 16 + cl, __float_as_uint(cm));
    }
  }
}

// ---------------------------------------------------------------------------
// Final: loss = -mean(log(sqrt(min_d2) + eps)), single block
// ---------------------------------------------------------------------------
__global__ __launch_bounds__(1024) void koleo_final(const unsigned int* __restrict__ minbits,
                                                    float* __restrict__ out) {
  __shared__ float wsum[16];
  float s = 0.f;
  for (int i = threadIdx.x; i < NROWS; i += 1024) {
    float d2 = __uint_as_float(minbits[i]);
    s += logf(sqrtf(d2) + 1e-8f);
  }
#pragma unroll
  for (int m = 32; m >= 1; m >>= 1) s += __shfl_xor(s, m, 64);
  const int wv = threadIdx.x >> 6, ln = threadIdx.x & 63;
  if (ln == 0) wsum[wv] = s;
  __syncthreads();
  if (wv == 0) {
    float t = (ln < 16) ? wsum[ln] : 0.f;
#pragma unroll
    for (int m = 8; m >= 1; m >>= 1) t += __shfl_xor(t, m, 64);
    if (ln == 0) out[0] = -t / (float)NROWS;
  }
}

// ---------------------------------------------------------------------------
extern "C" void kernel_launch(void* const* d_in, const int* in_sizes, int n_in,
                              void* d_out, int out_size, void* d_ws, size_t ws_size,
                              hipStream_t stream) {
  const float* X = (const float*)d_in[0];
  float* out = (float*)d_out;
  unsigned int* minbits = (unsigned int*)d_ws;                       // 32 KB
  float* sq = (float*)((char*)d_ws + NROWS * sizeof(unsigned int));  // 32 KB
  char* xbf = (char*)d_ws + 65536;                                   // 12.58 MB

  const size_t need = 65536 + PACKB;
  if (ws_size >= need) {
    koleo_pack<<<NRG, 256, 0, stream>>>(X, sq, minbits, xbf);
    koleo_frag<<<NBLK, 256, 0, stream>>>(xbf, sq, minbits);
  } else {
    koleo_prep_fb<<<NROWS / 4, 256, 0, stream>>>(X, sq, minbits);
    koleo_tile_fb<<<NT128 * (NT128 + 1) / 2, 256, 0, stream>>>(X, sq, minbits);
  }
  koleo_final<<<1, 1024, 0, stream>>>(minbits, out);
}

// Round 6
// 70.344 us; speedup vs baseline: 2.0601x; 2.0601x over previous
//
#include <hip/hip_runtime.h>
#include <hip/hip_bf16.h>
#include <math.h>

#define NROWS 8192
#define DIM   768
#define NKB   (DIM / 64)         // 12 k-chunks of 64
#define FCH   8192               // fp8 chunk: 128 rows x 64 cols = 8 KB
#define FPAN  (NKB * FCH)        // fp8 panel: 128 rows x 768 = 98304 B
#define NT128 (NROWS / 128)      // 64 row-blocks
#define NTILES (NT128 * (NT128 + 1) / 2)   // 2080 upper-tri tiles
#define PACK8B ((size_t)NT128 * FPAN)      // 6.29 MB

typedef __attribute__((ext_vector_type(4))) float  f32x4;
typedef __attribute__((ext_vector_type(8))) __bf16 bf16x8;
typedef __attribute__((ext_vector_type(4))) __bf16 bf16x4;

__device__ __forceinline__ void gload_lds16(const void* g, void* l) {
  __builtin_amdgcn_global_load_lds(
      (const __attribute__((address_space(1))) void*)g,
      (__attribute__((address_space(3))) void*)l, 16, 0, 0);
}

// ---------------------------------------------------------------------------
// Kernel A: fused fp8-pack + prep. One wave per row. f32 -> exact f32 sq-norm
// AND fp8 e4m3 conversion (HW v_cvt_pk_fp8_f32, RTNE+sat) into chunk layout
// with the LDS swizzle PRE-APPLIED:
//   chunk(rb, kb) = 128 rows x 64 cols; element (r,c) at byte
//   (r*64 + c) ^ ((r&7)<<3).   (4B stores sit inside an 8B granule: safe.)
// ---------------------------------------------------------------------------
__global__ __launch_bounds__(256) void koleo_pack8(const float* __restrict__ X,
                                                   float* __restrict__ sq,
                                                   unsigned int* __restrict__ minbits,
                                                   char* __restrict__ xbf) {
  const int row  = blockIdx.x * 4 + (threadIdx.x >> 6);
  const int lane = threadIdx.x & 63;
  const int rb = row >> 7, r = row & 127;
  const float* xr = X + (size_t)row * DIM;
  float s = 0.f;
#pragma unroll
  for (int i = 0; i < 3; ++i) {            // 768 = 3 * 64 lanes * 4 floats
    const int c0 = lane * 4 + i * 256;
    f32x4 v = *(const f32x4*)(xr + c0);
    s += v.x * v.x + v.y * v.y + v.z * v.z + v.w * v.w;
    int pk = __builtin_amdgcn_cvt_pk_fp8_f32(v.x, v.y, 0, false);
    pk     = __builtin_amdgcn_cvt_pk_fp8_f32(v.z, v.w, pk, true);
    const int kb = c0 >> 6;
    const int c  = c0 & 63;
    const int off = (r * 64 + c) ^ ((r & 7) << 3);
    *(int*)(xbf + (size_t)rb * FPAN + (size_t)kb * FCH + off) = pk;
  }
#pragma unroll
  for (int m = 32; m >= 1; m >>= 1) s += __shfl_xor(s, m, 64);
  if (lane == 0) {
    sq[row]      = s;
    minbits[row] = 0x7F800000u;            // +inf
  }
}

// ---------------------------------------------------------------------------
// Kernel B: 128x128 upper-triangular Gram tiles in fp8, R4's 2-phase
// double-buffered loop (validated): issue next K-chunk's 8 global_load_lds
// first, then 16 ds_read_b64 frags + 32 MFMA, then vmcnt(0) + one barrier.
// LDS: 2 x (A 8KB + B 8KB) = 32 KB dynamic.
// Tile ordering = L2-locality segments (not %8 swizzle):
//   [T(0:32): 528] [4 rects 32x8: 4x256] [T(32:64): 528]  — each segment's
//   panel footprint (3.1-3.9 MB fp8) fits one XCD L2.
// ---------------------------------------------------------------------------
__global__ __launch_bounds__(256, 3) void koleo_tile8f(const char* __restrict__ xbf,
                                                       const float* __restrict__ sq,
                                                       unsigned int* __restrict__ minbits) {
  extern __shared__ char lds[];            // 32768 bytes

  // segment-ordered tile map
  const int b = blockIdx.x;
  int ti, tj;
  if (b < 528) {                           // T0: panels [0,32)
    int rem = b, rl = 32; ti = 0;
    while (rem >= rl) { rem -= rl; ++ti; --rl; }
    tj = ti + rem;
  } else if (b < 1552) {                   // rect bands ti:[0,32) x tj:[32+8q,40+8q)
    const int q = (b - 528) >> 8, rr = (b - 528) & 255;
    ti = rr >> 3; tj = 32 + q * 8 + (rr & 7);
  } else {                                 // T1: panels [32,64)
    int rem = b - 1552, rl = 32; ti = 32;
    while (rem >= rl) { rem -= rl; ++ti; --rl; }
    tj = ti + rem;
  }
  const int i0 = ti * 128, j0 = tj * 128;

  const int tid  = threadIdx.x;
  const int lane = tid & 63;
  const int wave = tid >> 6;               // 0..3
  const int wr   = wave >> 1;              // row half
  const int wc   = wave & 1;               // col half

  const char* pA = xbf + (size_t)ti * FPAN + wave * 1024 + lane * 16;
  const char* pB = xbf + (size_t)tj * FPAN + wave * 1024 + lane * 16;

  f32x4 acc[4][4] = {};

  // ---- prologue: stage K-chunk 0 into buffer 0 ---------------------------
#pragma unroll
  for (int h = 0; h < 2; ++h) {
    gload_lds16(pA + h * 4096, lds +        h * 4096 + wave * 1024);
    gload_lds16(pB + h * 4096, lds + 8192 + h * 4096 + wave * 1024);
  }
  asm volatile("s_waitcnt vmcnt(0)" ::: "memory");
  __builtin_amdgcn_s_barrier();

  // ---- main K-loop: one barrier per K-chunk ------------------------------
  for (int t = 0; t < NKB; ++t) {
    char* buf  = lds + (t & 1) * 16384;
    char* nbuf = lds + ((t + 1) & 1) * 16384;
    const bool more = (t + 1 < NKB);

    if (more) {                            // issue next-chunk staging FIRST
      const char* sA = pA + (size_t)(t + 1) * FCH;
      const char* sB = pB + (size_t)(t + 1) * FCH;
#pragma unroll
      for (int h = 0; h < 2; ++h) {
        gload_lds16(sA + h * 4096, nbuf +        h * 4096 + wave * 1024);
        gload_lds16(sB + h * 4096, nbuf + 8192 + h * 4096 + wave * 1024);
      }
    }

#pragma unroll
    for (int ks = 0; ks < 2; ++ks) {       // two K=32 slices per chunk
      long af[4], bq[4];
#pragma unroll
      for (int m = 0; m < 4; ++m) {
        const int ra = wr * 64 + m * 16 + (lane & 15);
        af[m] = *(const long*)(buf + ((ra * 64 + ks * 32 + (lane >> 4) * 8) ^ ((ra & 7) << 3)));
        const int rb2 = wc * 64 + m * 16 + (lane & 15);
        bq[m] = *(const long*)(buf + 8192 + ((rb2 * 64 + ks * 32 + (lane >> 4) * 8) ^ ((rb2 & 7) << 3)));
      }
#pragma unroll
      for (int m = 0; m < 4; ++m)
#pragma unroll
        for (int n = 0; n < 4; ++n)
          acc[m][n] = __builtin_amdgcn_mfma_f32_16x16x32_fp8_fp8(af[m], bq[n], acc[m][n], 0, 0, 0);
    }

    if (more) asm volatile("s_waitcnt vmcnt(0)" ::: "memory");
    __builtin_amdgcn_s_barrier();
  }

  // ---- epilogue: d2, diagonal mask, row-min + col-min, atomicMin ----------
  // C/D layout (m89, dtype-independent): col = lane&15, row = (lane>>4)*4+reg
  const int cg = lane >> 4;
  const int cl = lane & 15;
  float sqj[4], colmin[4];
#pragma unroll
  for (int n = 0; n < 4; ++n) {
    sqj[n]    = sq[j0 + wc * 64 + n * 16 + cl];
    colmin[n] = INFINITY;
  }
#pragma unroll
  for (int m = 0; m < 4; ++m) {
#pragma unroll
    for (int r = 0; r < 4; ++r) {
      const int gi = i0 + wr * 64 + m * 16 + cg * 4 + r;
      const float si = sq[gi];
      float rowmin = INFINITY;
#pragma unroll
      for (int n = 0; n < 4; ++n) {
        const int gj = j0 + wc * 64 + n * 16 + cl;
        float d2 = si + sqj[n] - 2.0f * acc[m][n][r];
        d2 = fmaxf(d2, 0.0f);
        if (gi == gj) d2 = INFINITY;
        rowmin    = fminf(rowmin, d2);
        colmin[n] = fminf(colmin[n], d2);
      }
      rowmin = fminf(rowmin, __shfl_xor(rowmin, 1, 64));
      rowmin = fminf(rowmin, __shfl_xor(rowmin, 2, 64));
      rowmin = fminf(rowmin, __shfl_xor(rowmin, 4, 64));
      rowmin = fminf(rowmin, __shfl_xor(rowmin, 8, 64));
      if (cl == 0)
        atomicMin(minbits + gi, __float_as_uint(rowmin));
    }
  }
  if (ti != tj) {
#pragma unroll
    for (int n = 0; n < 4; ++n) {
      float cm = colmin[n];
      cm = fminf(cm, __shfl_xor(cm, 16, 64));
      cm = fminf(cm, __shfl_xor(cm, 32, 64));
      if (cg == 0)
        atomicMin(minbits + j0 + wc * 64 + n * 16 + cl, __float_as_uint(cm));
    }
  }
}

// ---------------------------------------------------------------------------
// Fallback (ws too small): bf16 f32-load + in-loop cvt staging, 128^2 tiles.
// ---------------------------------------------------------------------------
__global__ __launch_bounds__(256) void koleo_prep_fb(const float* __restrict__ X,
                                                     float* __restrict__ sq,
                                                     unsigned int* __restrict__ minbits) {
  const int row  = blockIdx.x * 4 + (threadIdx.x >> 6);
  const int lane = threadIdx.x & 63;
  const float* xr = X + (size_t)row * DIM;
  float s = 0.f;
#pragma unroll
  for (int i = 0; i < 3; ++i) {
    f32x4 v = *(const f32x4*)(xr + lane * 4 + i * 256);
    s += v.x * v.x + v.y * v.y + v.z * v.z + v.w * v.w;
  }
#pragma unroll
  for (int m = 32; m >= 1; m >>= 1) s += __shfl_xor(s, m, 64);
  if (lane == 0) { sq[row] = s; minbits[row] = 0x7F800000u; }
}

__global__ __launch_bounds__(256) void koleo_tile_fb(const float* __restrict__ X,
                                                     const float* __restrict__ sq,
                                                     unsigned int* __restrict__ minbits) {
  __shared__ __align__(16) char sA[16384];
  __shared__ __align__(16) char sB[16384];
  int rem = blockIdx.x, ti = 0, rowlen = NT128;
  while (rem >= rowlen) { rem -= rowlen; ++ti; --rowlen; }
  const int tj = ti + rem;
  const int i0 = ti * 128, j0 = tj * 128;
  const int tid = threadIdx.x, lane = tid & 63, wave = tid >> 6;
  const int wr = wave >> 1, wc = wave & 1;
  f32x4 acc[4][4] = {};
  for (int k0 = 0; k0 < DIM; k0 += 64) {
    __syncthreads();
#pragma unroll
    for (int it = 0; it < 8; ++it) {
      const int idx = tid + it * 256;
      const int r = idx >> 4, c4 = idx & 15;
      f32x4 va = *(const f32x4*)(X + (size_t)(i0 + r) * DIM + k0 + c4 * 4);
      f32x4 vb = *(const f32x4*)(X + (size_t)(j0 + r) * DIM + k0 + c4 * 4);
      bf16x4 ha, hb;
      ha[0] = (__bf16)va.x; ha[1] = (__bf16)va.y; ha[2] = (__bf16)va.z; ha[3] = (__bf16)va.w;
      hb[0] = (__bf16)vb.x; hb[1] = (__bf16)vb.y; hb[2] = (__bf16)vb.z; hb[3] = (__bf16)vb.w;
      int off = (r * 128 + c4 * 8) ^ ((r & 7) << 4);
      *(bf16x4*)(sA + off) = ha;
      *(bf16x4*)(sB + off) = hb;
    }
    __syncthreads();
#pragma unroll
    for (int ks = 0; ks < 2; ++ks) {
      bf16x8 af[4], bfr[4];
#pragma unroll
      for (int m = 0; m < 4; ++m) {
        const int ra = wr * 64 + m * 16 + (lane & 15);
        af[m]  = *(const bf16x8*)(sA + ((ra * 128 + ks * 64 + (lane >> 4) * 16) ^ ((ra & 7) << 4)));
        const int rb2 = wc * 64 + m * 16 + (lane & 15);
        bfr[m] = *(const bf16x8*)(sB + ((rb2 * 128 + ks * 64 + (lane >> 4) * 16) ^ ((rb2 & 7) << 4)));
      }
#pragma unroll
      for (int m = 0; m < 4; ++m)
#pragma unroll
        for (int n = 0; n < 4; ++n)
          acc[m][n] = __builtin_amdgcn_mfma_f32_16x16x32_bf16(af[m], bfr[n], acc[m][n], 0, 0, 0);
    }
  }
  const int cg = lane >> 4, cl = lane & 15;
  float sqj[4], colmin[4];
#pragma unroll
  for (int n = 0; n < 4; ++n) { sqj[n] = sq[j0 + wc * 64 + n * 16 + cl]; colmin[n] = INFINITY; }
#pragma unroll
  for (int m = 0; m < 4; ++m) {
#pragma unroll
    for (int r = 0; r < 4; ++r) {
      const int gi = i0 + wr * 64 + m * 16 + cg * 4 + r;
      const float si = sq[gi];
      float rowmin = INFINITY;
#pragma unroll
      for (int n = 0; n < 4; ++n) {
        const int gj = j0 + wc * 64 + n * 16 + cl;
        float d2 = si + sqj[n] - 2.0f * acc[m][n][r];
        d2 = fmaxf(d2, 0.0f);
        if (gi == gj) d2 = INFINITY;
        rowmin = fminf(rowmin, d2);
        colmin[n] = fminf(colmin[n], d2);
      }
      rowmin = fminf(rowmin, __shfl_xor(rowmin, 1, 64));
      rowmin = fminf(rowmin, __shfl_xor(rowmin, 2, 64));
      rowmin = fminf(rowmin, __shfl_xor(rowmin, 4, 64));
      rowmin = fminf(rowmin, __shfl_xor(rowmin, 8, 64));
      if (cl == 0) atomicMin(minbits + gi, __float_as_uint(rowmin));
    }
  }
  if (ti != tj) {
#pragma unroll
    for (int n = 0; n < 4; ++n) {
      float cm = colmin[n];
      cm = fminf(cm, __shfl_xor(cm, 16, 64));
      cm = fminf(cm, __shfl_xor(cm, 32, 64));
      if (cg == 0) atomicMin(minbits + j0 + wc * 64 + n * 16 + cl, __float_as_uint(cm));
    }
  }
}

// ---------------------------------------------------------------------------
// Final: loss = -mean(log(sqrt(min_d2) + eps)), single block
// ---------------------------------------------------------------------------
__global__ __launch_bounds__(1024) void koleo_final(const unsigned int* __restrict__ minbits,
                                                    float* __restrict__ out) {
  __shared__ float wsum[16];
  float s = 0.f;
  for (int i = threadIdx.x; i < NROWS; i += 1024) {
    float d2 = __uint_as_float(minbits[i]);
    s += logf(sqrtf(d2) + 1e-8f);
  }
#pragma unroll
  for (int m = 32; m >= 1; m >>= 1) s += __shfl_xor(s, m, 64);
  const int wv = threadIdx.x >> 6, ln = threadIdx.x & 63;
  if (ln == 0) wsum[wv] = s;
  __syncthreads();
  if (wv == 0) {
    float t = (ln < 16) ? wsum[ln] : 0.f;
#pragma unroll
    for (int m = 8; m >= 1; m >>= 1) t += __shfl_xor(t, m, 64);
    if (ln == 0) out[0] = -t / (float)NROWS;
  }
}

// ---------------------------------------------------------------------------
extern "C" void kernel_launch(void* const* d_in, const int* in_sizes, int n_in,
                              void* d_out, int out_size, void* d_ws, size_t ws_size,
                              hipStream_t stream) {
  const float* X = (const float*)d_in[0];
  float* out = (float*)d_out;
  unsigned int* minbits = (unsigned int*)d_ws;                       // 32 KB
  float* sq = (float*)((char*)d_ws + NROWS * sizeof(unsigned int));  // 32 KB
  char* xbf = (char*)d_ws + 65536;                                   // 6.29 MB

  const size_t need = 65536 + PACK8B;
  if (ws_size >= need) {
    koleo_pack8<<<NROWS / 4, 256, 0, stream>>>(X, sq, minbits, xbf);
    koleo_tile8f<<<NTILES, 256, 32768, stream>>>(xbf, sq, minbits);
  } else {
    koleo_prep_fb<<<NROWS / 4, 256, 0, stream>>>(X, sq, minbits);
    koleo_tile_fb<<<NTILES, 256, 0, stream>>>(X, sq, minbits);
  }
  koleo_final<<<1, 1024, 0, stream>>>(minbits, out);
}

// Round 7
// 65.164 us; speedup vs baseline: 2.2239x; 1.0795x over previous
//
#include <hip/hip_runtime.h>
#include <hip/hip_bf16.h>
#include <math.h>

#define NROWS 8192
#define DIM   768
#define NKB   (DIM / 64)         // 12 k-chunks of 64
#define FCH   8192               // fp8 chunk: 128 rows x 64 cols = 8 KB
#define FPAN  (NKB * FCH)        // fp8 panel: 128 rows x 768 = 98304 B
#define NT128 (NROWS / 128)      // 64 row-blocks
#define NTILES (NT128 * (NT128 + 1) / 2)   // 2080 upper-tri tiles
#define PACK8B ((size_t)NT128 * FPAN)      // 6.29 MB

typedef __attribute__((ext_vector_type(4))) float  f32x4;
typedef __attribute__((ext_vector_type(8))) __bf16 bf16x8;
typedef __attribute__((ext_vector_type(4))) __bf16 bf16x4;
typedef __attribute__((ext_vector_type(2))) long   longx2;

__device__ __forceinline__ void gload_lds16(const void* g, void* l) {
  __builtin_amdgcn_global_load_lds(
      (const __attribute__((address_space(1))) void*)g,
      (__attribute__((address_space(3))) void*)l, 16, 0, 0);
}

// ---------------------------------------------------------------------------
// Kernel A: fused fp8-pack + prep. One wave per row. f32 -> exact f32 sq-norm
// AND fp8 e4m3 conversion (HW v_cvt_pk_fp8_f32) into INTERLEAVED chunk layout
// with the LDS swizzle PRE-APPLIED.
//   chunk(rb, kb) = 128 rows x 64 k-bytes. Within a row, k = ks*32 + g*8 + b
//   (ks in 0..1, g in 0..3, b in 0..7) is stored at pos = g*16 + ks*8 + b,
//   so ONE 16B read at pos=g*16 yields both k-slices' MFMA fragments.
//   Swizzle: off = (r*64 + pos) ^ (((r>>1)&3)<<4)  — rows 0..7 cover all 32
//   banks once for a b128 fragment read (2-way for 16 rows = free, m136);
//   XOR touches bit 4 only -> 16B/4B alignment preserved.
// ---------------------------------------------------------------------------
__global__ __launch_bounds__(256) void koleo_pack8(const float* __restrict__ X,
                                                   float* __restrict__ sq,
                                                   unsigned int* __restrict__ minbits,
                                                   char* __restrict__ xbf) {
  const int row  = blockIdx.x * 4 + (threadIdx.x >> 6);
  const int lane = threadIdx.x & 63;
  const int rb = row >> 7, r = row & 127;
  const float* xr = X + (size_t)row * DIM;
  float s = 0.f;
#pragma unroll
  for (int i = 0; i < 3; ++i) {            // 768 = 3 * 64 lanes * 4 floats
    const int c0 = lane * 4 + i * 256;
    f32x4 v = *(const f32x4*)(xr + c0);
    s += v.x * v.x + v.y * v.y + v.z * v.z + v.w * v.w;
    int pk = __builtin_amdgcn_cvt_pk_fp8_f32(v.x, v.y, 0, false);
    pk     = __builtin_amdgcn_cvt_pk_fp8_f32(v.z, v.w, pk, true);
    const int kb = c0 >> 6;                // chunk index
    const int c  = c0 & 63;                // k within chunk
    const int ks = c >> 5;                 // k-slice 0..1
    const int g  = (c >> 3) & 3;           // lane-quarter group
    const int bb = c & 7;                  // byte in fragment (0 or 4)
    const int pos = g * 16 + ks * 8 + bb;  // interleaved position
    const int off = (r * 64 + pos) ^ (((r >> 1) & 3) << 4);
    *(int*)(xbf + (size_t)rb * FPAN + (size_t)kb * FCH + off) = pk;
  }
#pragma unroll
  for (int m = 32; m >= 1; m >>= 1) s += __shfl_xor(s, m, 64);
  if (lane == 0) {
    sq[row]      = s;
    minbits[row] = 0x7F800000u;            // +inf
  }
}

// ---------------------------------------------------------------------------
// Kernel B: 128x128 upper-triangular Gram tiles in fp8, 2-phase double-
// buffered loop (validated R4/R6): issue next K-chunk's global_load_lds
// first, then 8x ds_read_b128 frags + 32 MFMA, then vmcnt(0) + one barrier.
// LDS: 2 x (A 8KB + B 8KB) = 32 KB dynamic; 4 blocks/CU.
// Tile ordering = L2-locality segments (validated R6):
//   [T(0:32): 528] [4 rects 32x8: 4x256] [T(32:64): 528]
// ---------------------------------------------------------------------------
__global__ __launch_bounds__(256, 4) void koleo_tile8f(const char* __restrict__ xbf,
                                                       const float* __restrict__ sq,
                                                       unsigned int* __restrict__ minbits) {
  extern __shared__ char lds[];            // 32768 bytes

  // segment-ordered tile map
  const int b = blockIdx.x;
  int ti, tj;
  if (b < 528) {                           // T0: panels [0,32)
    int rem = b, rl = 32; ti = 0;
    while (rem >= rl) { rem -= rl; ++ti; --rl; }
    tj = ti + rem;
  } else if (b < 1552) {                   // rect bands ti:[0,32) x tj:[32+8q,40+8q)
    const int q = (b - 528) >> 8, rr = (b - 528) & 255;
    ti = rr >> 3; tj = 32 + q * 8 + (rr & 7);
  } else {                                 // T1: panels [32,64)
    int rem = b - 1552, rl = 32; ti = 32;
    while (rem >= rl) { rem -= rl; ++ti; --rl; }
    tj = ti + rem;
  }
  const int i0 = ti * 128, j0 = tj * 128;

  const int tid  = threadIdx.x;
  const int lane = tid & 63;
  const int wave = tid >> 6;               // 0..3
  const int wr   = wave >> 1;              // row half
  const int wc   = wave & 1;               // col half
  const int g16  = (lane >> 4) * 16;       // fragment 16B group offset

  const char* pA = xbf + (size_t)ti * FPAN + wave * 1024 + lane * 16;
  const char* pB = xbf + (size_t)tj * FPAN + wave * 1024 + lane * 16;

  f32x4 acc[4][4] = {};

  // ---- prologue: stage K-chunk 0 into buffer 0 ---------------------------
#pragma unroll
  for (int h = 0; h < 2; ++h) {
    gload_lds16(pA + h * 4096, lds +        h * 4096 + wave * 1024);
    gload_lds16(pB + h * 4096, lds + 8192 + h * 4096 + wave * 1024);
  }
  asm volatile("s_waitcnt vmcnt(0)" ::: "memory");
  __builtin_amdgcn_s_barrier();

  // ---- main K-loop: one barrier per K-chunk ------------------------------
  for (int t = 0; t < NKB; ++t) {
    char* buf  = lds + (t & 1) * 16384;
    char* nbuf = lds + ((t + 1) & 1) * 16384;
    const bool more = (t + 1 < NKB);

    if (more) {                            // issue next-chunk staging FIRST
      const char* sA = pA + (size_t)(t + 1) * FCH;
      const char* sB = pB + (size_t)(t + 1) * FCH;
#pragma unroll
      for (int h = 0; h < 2; ++h) {
        gload_lds16(sA + h * 4096, nbuf +        h * 4096 + wave * 1024);
        gload_lds16(sB + h * 4096, nbuf + 8192 + h * 4096 + wave * 1024);
      }
    }

    // 8x ds_read_b128: each 16B = [ks0 frag | ks1 frag] for one row
    longx2 aP[4], bP[4];
#pragma unroll
    for (int m = 0; m < 4; ++m) {
      const int ra = wr * 64 + m * 16 + (lane & 15);
      aP[m] = *(const longx2*)(buf + ((ra * 64 + g16) ^ (((ra >> 1) & 3) << 4)));
      const int rb2 = wc * 64 + m * 16 + (lane & 15);
      bP[m] = *(const longx2*)(buf + 8192 + ((rb2 * 64 + g16) ^ (((rb2 >> 1) & 3) << 4)));
    }
#pragma unroll
    for (int ks = 0; ks < 2; ++ks)
#pragma unroll
      for (int m = 0; m < 4; ++m)
#pragma unroll
        for (int n = 0; n < 4; ++n)
          acc[m][n] = __builtin_amdgcn_mfma_f32_16x16x32_fp8_fp8(aP[m][ks], bP[n][ks], acc[m][n], 0, 0, 0);

    if (more) asm volatile("s_waitcnt vmcnt(0)" ::: "memory");
    __builtin_amdgcn_s_barrier();
  }

  // ---- epilogue: d2, diagonal mask, row-min + col-min, atomicMin ----------
  // C/D layout (m89, dtype-independent): col = lane&15, row = (lane>>4)*4+reg
  const int cg = lane >> 4;
  const int cl = lane & 15;
  float sqj[4], colmin[4];
#pragma unroll
  for (int n = 0; n < 4; ++n) {
    sqj[n]    = sq[j0 + wc * 64 + n * 16 + cl];
    colmin[n] = INFINITY;
  }
#pragma unroll
  for (int m = 0; m < 4; ++m) {
#pragma unroll
    for (int r = 0; r < 4; ++r) {
      const int gi = i0 + wr * 64 + m * 16 + cg * 4 + r;
      const float si = sq[gi];
      float rowmin = INFINITY;
#pragma unroll
      for (int n = 0; n < 4; ++n) {
        const int gj = j0 + wc * 64 + n * 16 + cl;
        float d2 = si + sqj[n] - 2.0f * acc[m][n][r];
        d2 = fmaxf(d2, 0.0f);
        if (gi == gj) d2 = INFINITY;
        rowmin    = fminf(rowmin, d2);
        colmin[n] = fminf(colmin[n], d2);
      }
      rowmin = fminf(rowmin, __shfl_xor(rowmin, 1, 64));
      rowmin = fminf(rowmin, __shfl_xor(rowmin, 2, 64));
      rowmin = fminf(rowmin, __shfl_xor(rowmin, 4, 64));
      rowmin = fminf(rowmin, __shfl_xor(rowmin, 8, 64));
      if (cl == 0)
        atomicMin(minbits + gi, __float_as_uint(rowmin));
    }
  }
  if (ti != tj) {
#pragma unroll
    for (int n = 0; n < 4; ++n) {
      float cm = colmin[n];
      cm = fminf(cm, __shfl_xor(cm, 16, 64));
      cm = fminf(cm, __shfl_xor(cm, 32, 64));
      if (cg == 0)
        atomicMin(minbits + j0 + wc * 64 + n * 16 + cl, __float_as_uint(cm));
    }
  }
}

// ---------------------------------------------------------------------------
// Fallback (ws too small): bf16 f32-load + in-loop cvt staging, 128^2 tiles.
// ---------------------------------------------------------------------------
__global__ __launch_bounds__(256) void koleo_prep_fb(const float* __restrict__ X,
                                                     float* __restrict__ sq,
                                                     unsigned int* __restrict__ minbits) {
  const int row  = blockIdx.x * 4 + (threadIdx.x >> 6);
  const int lane = threadIdx.x & 63;
  const float* xr = X + (size_t)row * DIM;
  float s = 0.f;
#pragma unroll
  for (int i = 0; i < 3; ++i) {
    f32x4 v = *(const f32x4*)(xr + lane * 4 + i * 256);
    s += v.x * v.x + v.y * v.y + v.z * v.z + v.w * v.w;
  }
#pragma unroll
  for (int m = 32; m >= 1; m >>= 1) s += __shfl_xor(s, m, 64);
  if (lane == 0) { sq[row] = s; minbits[row] = 0x7F800000u; }
}

__global__ __launch_bounds__(256) void koleo_tile_fb(const float* __restrict__ X,
                                                     const float* __restrict__ sq,
                                                     unsigned int* __restrict__ minbits) {
  __shared__ __align__(16) char sA[16384];
  __shared__ __align__(16) char sB[16384];
  int rem = blockIdx.x, ti = 0, rowlen = NT128;
  while (rem >= rowlen) { rem -= rowlen; ++ti; --rowlen; }
  const int tj = ti + rem;
  const int i0 = ti * 128, j0 = tj * 128;
  const int tid = threadIdx.x, lane = tid & 63, wave = tid >> 6;
  const int wr = wave >> 1, wc = wave & 1;
  f32x4 acc[4][4] = {};
  for (int k0 = 0; k0 < DIM; k0 += 64) {
    __syncthreads();
#pragma unroll
    for (int it = 0; it < 8; ++it) {
      const int idx = tid + it * 256;
      const int r = idx >> 4, c4 = idx & 15;
      f32x4 va = *(const f32x4*)(X + (size_t)(i0 + r) * DIM + k0 + c4 * 4);
      f32x4 vb = *(const f32x4*)(X + (size_t)(j0 + r) * DIM + k0 + c4 * 4);
      bf16x4 ha, hb;
      ha[0] = (__bf16)va.x; ha[1] = (__bf16)va.y; ha[2] = (__bf16)va.z; ha[3] = (__bf16)va.w;
      hb[0] = (__bf16)vb.x; hb[1] = (__bf16)vb.y; hb[2] = (__bf16)vb.z; hb[3] = (__bf16)vb.w;
      int off = (r * 128 + c4 * 8) ^ ((r & 7) << 4);
      *(bf16x4*)(sA + off) = ha;
      *(bf16x4*)(sB + off) = hb;
    }
    __syncthreads();
#pragma unroll
    for (int ks = 0; ks < 2; ++ks) {
      bf16x8 af[4], bfr[4];
#pragma unroll
      for (int m = 0; m < 4; ++m) {
        const int ra = wr * 64 + m * 16 + (lane & 15);
        af[m]  = *(const bf16x8*)(sA + ((ra * 128 + ks * 64 + (lane >> 4) * 16) ^ ((ra & 7) << 4)));
        const int rb2 = wc * 64 + m * 16 + (lane & 15);
        bfr[m] = *(const bf16x8*)(sB + ((rb2 * 128 + ks * 64 + (lane >> 4) * 16) ^ ((rb2 & 7) << 4)));
      }
#pragma unroll
      for (int m = 0; m < 4; ++m)
#pragma unroll
        for (int n = 0; n < 4; ++n)
          acc[m][n] = __builtin_amdgcn_mfma_f32_16x16x32_bf16(af[m], bfr[n], acc[m][n], 0, 0, 0);
    }
  }
  const int cg = lane >> 4, cl = lane & 15;
  float sqj[4], colmin[4];
#pragma unroll
  for (int n = 0; n < 4; ++n) { sqj[n] = sq[j0 + wc * 64 + n * 16 + cl]; colmin[n] = INFINITY; }
#pragma unroll
  for (int m = 0; m < 4; ++m) {
#pragma unroll
    for (int r = 0; r < 4; ++r) {
      const int gi = i0 + wr * 64 + m * 16 + cg * 4 + r;
      const float si = sq[gi];
      float rowmin = INFINITY;
#pragma unroll
      for (int n = 0; n < 4; ++n) {
        const int gj = j0 + wc * 64 + n * 16 + cl;
        float d2 = si + sqj[n] - 2.0f * acc[m][n][r];
        d2 = fmaxf(d2, 0.0f);
        if (gi == gj) d2 = INFINITY;
        rowmin = fminf(rowmin, d2);
        colmin[n] = fminf(colmin[n], d2);
      }
      rowmin = fminf(rowmin, __shfl_xor(rowmin, 1, 64));
      rowmin = fminf(rowmin, __shfl_xor(rowmin, 2, 64));
      rowmin = fminf(rowmin, __shfl_xor(rowmin, 4, 64));
      rowmin = fminf(rowmin, __shfl_xor(rowmin, 8, 64));
      if (cl == 0) atomicMin(minbits + gi, __float_as_uint(rowmin));
    }
  }
  if (ti != tj) {
#pragma unroll
    for (int n = 0; n < 4; ++n) {
      float cm = colmin[n];
      cm = fminf(cm, __shfl_xor(cm, 16, 64));
      cm = fminf(cm, __shfl_xor(cm, 32, 64));
      if (cg == 0) atomicMin(minbits + j0 + wc * 64 + n * 16 + cl, __float_as_uint(cm));
    }
  }
}

// ---------------------------------------------------------------------------
// Final: loss = -mean(log(sqrt(min_d2) + eps)), single block
// ---------------------------------------------------------------------------
__global__ __launch_bounds__(1024) void koleo_final(const unsigned int* __restrict__ minbits,
                                                    float* __restrict__ out) {
  __shared__ float wsum[16];
  float s = 0.f;
  for (int i = threadIdx.x; i < NROWS; i += 1024) {
    float d2 = __uint_as_float(minbits[i]);
    s += logf(sqrtf(d2) + 1e-8f);
  }
#pragma unroll
  for (int m = 32; m >= 1; m >>= 1) s += __shfl_xor(s, m, 64);
  const int wv = threadIdx.x >> 6, ln = threadIdx.x & 63;
  if (ln == 0) wsum[wv] = s;
  __syncthreads();
  if (wv == 0) {
    float t = (ln < 16) ? wsum[ln] : 0.f;
#pragma unroll
    for (int m = 8; m >= 1; m >>= 1) t += __shfl_xor(t, m, 64);
    if (ln == 0) out[0] = -t / (float)NROWS;
  }
}

// ---------------------------------------------------------------------------
extern "C" void kernel_launch(void* const* d_in, const int* in_sizes, int n_in,
                              void* d_out, int out_size, void* d_ws, size_t ws_size,
                              hipStream_t stream) {
  const float* X = (const float*)d_in[0];
  float* out = (float*)d_out;
  unsigned int* minbits = (unsigned int*)d_ws;                       // 32 KB
  float* sq = (float*)((char*)d_ws + NROWS * sizeof(unsigned int));  // 32 KB
  char* xbf = (char*)d_ws + 65536;                                   // 6.29 MB

  const size_t need = 65536 + PACK8B;
  if (ws_size >= need) {
    koleo_pack8<<<NROWS / 4, 256, 0, stream>>>(X, sq, minbits, xbf);
    koleo_tile8f<<<NTILES, 256, 32768, stream>>>(xbf, sq, minbits);
  } else {
    koleo_prep_fb<<<NROWS / 4, 256, 0, stream>>>(X, sq, minbits);
    koleo_tile_fb<<<NTILES, 256, 0, stream>>>(X, sq, minbits);
  }
  koleo_final<<<1, 1024, 0, stream>>>(minbits, out);
}